// Round 10
// baseline (649.185 us; speedup 1.0000x reference)
//
#include <hip/hip_runtime.h>
#include <math.h>
#include <stdint.h>

#define N_NODES 50000
#define N_EDGES 800000
#define D 128
#define GR 50
#define EPSV 1e-5f

typedef __attribute__((ext_vector_type(8))) short bf16x8;
typedef __attribute__((ext_vector_type(4))) float f32x4;

__device__ __forceinline__ float lrelu(float v){ return v > 0.f ? v : 0.2f*v; }

__device__ __forceinline__ unsigned int f2bf(float f){
  union { float f; uint32_t i; } v; v.f = f;
  uint32_t r = v.i + 0x7fffu + ((v.i >> 16) & 1u);
  return r >> 16;
}
__device__ __forceinline__ float2 bf2f2(uint32_t u){
  union { uint32_t i; float f; } a, b;
  a.i = u << 16;
  b.i = u & 0xffff0000u;
  return make_float2(a.f, b.f);
}

// ---------------- CSR build (one atomic pass) ----------------
__global__ void k_countrank(const int* __restrict__ dst, int* __restrict__ deg,
                            int* __restrict__ rank){
  int e = blockIdx.x*256 + threadIdx.x;
  if (e < N_EDGES) rank[e] = atomicAdd(&deg[dst[e]], 1);
}
__global__ void k_scan1(const int* __restrict__ deg, int* __restrict__ bsum){
  __shared__ int s[256];
  int i = blockIdx.x*256 + threadIdx.x;
  int v = (i < N_NODES) ? deg[i] : 0;
  s[threadIdx.x] = v; __syncthreads();
  for (int off = 128; off > 0; off >>= 1){
    if (threadIdx.x < off) s[threadIdx.x] += s[threadIdx.x + off];
    __syncthreads();
  }
  if (threadIdx.x == 0) bsum[blockIdx.x] = s[0];
}
__global__ void k_scan2b(int* __restrict__ bsum, int nb, int* __restrict__ rowStart){
  __shared__ int s[256];
  int t = threadIdx.x;
  int v = (t < nb) ? bsum[t] : 0;
  s[t] = v; __syncthreads();
  for (int off = 1; off < 256; off <<= 1){
    int xv = (t >= off) ? s[t - off] : 0;
    __syncthreads();
    s[t] += xv;
    __syncthreads();
  }
  if (t < nb) bsum[t] = s[t] - v;
  if (t == 255) rowStart[N_NODES] = s[255];
}
__global__ void k_scan3(const int* __restrict__ deg, const int* __restrict__ bsum,
                        int* __restrict__ rowStart){
  __shared__ int s[256];
  int i = blockIdx.x*256 + threadIdx.x;
  int v = (i < N_NODES) ? deg[i] : 0;
  s[threadIdx.x] = v; __syncthreads();
  for (int off = 1; off < 256; off <<= 1){
    int xv = (threadIdx.x >= off) ? s[threadIdx.x - off] : 0;
    __syncthreads();
    s[threadIdx.x] += xv;
    __syncthreads();
  }
  if (i < N_NODES) rowStart[i] = bsum[blockIdx.x] + s[threadIdx.x] - v;
}
__global__ void k_scatter(const int* __restrict__ src, const int* __restrict__ dst,
                          const int* __restrict__ rank, const int* __restrict__ rowStart,
                          int* __restrict__ srcList){
  int e = blockIdx.x*256 + threadIdx.x;
  if (e < N_EDGES)
    srcList[rowStart[dst[e]] + rank[e]] = src[e];
}

// ---------------- fused casts: weights (640 blocks) + x (rest) ----------------
struct WPack { const float* w[10]; };
__global__ void k_casts(WPack p, unsigned short* __restrict__ wt,
                        const float* __restrict__ x, unsigned short* __restrict__ x16){
  int b = blockIdx.x;
  if (b < 640){
    int mat = b >> 6;
    int local = (b & 63)*256 + threadIdx.x;
    int c = local >> 7, k = local & 127;
    wt[(size_t)mat*16384 + c*128 + k] = (unsigned short)f2bf(p.w[mat][k*128 + c]);
  } else {
    int idx = (b - 640)*256 + threadIdx.x;
    if (idx >= N_NODES*32) return;
    float4 v = *(const float4*)(x + (size_t)idx*4);
    uint2 pk;
    pk.x = f2bf(v.x) | (f2bf(v.y) << 16);
    pk.y = f2bf(v.z) | (f2bf(v.w) << 16);
    *(uint2*)(x16 + (size_t)idx*4) = pk;
  }
}

// ======================= MFMA GEMM family =======================
__device__ __forceinline__ void stage_w(const unsigned short* __restrict__ wt,
                                        unsigned short* __restrict__ lds, int t){
  #pragma unroll
  for (int i = 0; i < 8; ++i){
    int ch = i*256 + t;
    int col = ch >> 4, kc = ch & 15;
    *(uint4*)(&lds[col*136 + kc*8]) = *(const uint4*)(wt + ((size_t)col << 7) + (kc << 3));
  }
}

__device__ __forceinline__ void load_a(const unsigned short* __restrict__ xrow,
                                       int quad, bf16x8 a[4]){
  #pragma unroll
  for (int ks = 0; ks < 4; ++ks)
    a[ks] = *(const bf16x8*)(xrow + ks*32 + quad*8);
}

__device__ __forceinline__ void mfma_regs(const bf16x8 a[4],
                                          const unsigned short* __restrict__ lds,
                                          int lane, f32x4 acc[8]){
  int quad = lane >> 4, m = lane & 15;
  #pragma unroll
  for (int ks = 0; ks < 4; ++ks){
    #pragma unroll
    for (int nt = 0; nt < 8; ++nt){
      bf16x8 b = *(const bf16x8*)(&lds[(nt*16 + m)*136 + ks*32 + quad*8]);
      acc[nt] = __builtin_amdgcn_mfma_f32_16x16x32_bf16(a[ks], b, acc[nt], 0, 0, 0);
    }
  }
}

__device__ __forceinline__ void epi_store16(f32x4 acc[8], const float* bias,
    unsigned short* __restrict__ ldsw, unsigned short* __restrict__ Y16,
    int rbase, int lane, int n){
  int quad = lane >> 4, m = lane & 15;
  #pragma unroll
  for (int nt = 0; nt < 8; ++nt){
    int col = nt*16 + m;
    float bv = bias ? bias[col] : 0.f;
    #pragma unroll
    for (int reg = 0; reg < 4; ++reg)
      ldsw[(quad*4 + reg)*132 + col] = (unsigned short)f2bf(acc[nt][reg] + bv);
  }
  int r = lane >> 2, seg = lane & 3;
  int grow = rbase + r;
  if (grow < n){
    unsigned short* gp = Y16 + (size_t)grow*128 + seg*32;
    #pragma unroll
    for (int j = 0; j < 4; ++j)
      *(uint4*)(gp + j*8) = *(const uint4*)(&ldsw[r*132 + seg*32 + j*8]);
  }
}

// ---- GAT-layer dual GEMM: R16 = bf16(X@Wres + bres); H16 = bf16(X@Wgat); es/ed
__global__ __launch_bounds__(256) void k_mgemm_dual(const unsigned short* __restrict__ X16,
    const unsigned short* __restrict__ wtres, const unsigned short* __restrict__ wtgat,
    const float* __restrict__ bres, const float* __restrict__ as_,
    const float* __restrict__ ad_, unsigned short* __restrict__ R16,
    unsigned short* __restrict__ H16, float* __restrict__ es, float* __restrict__ ed,
    int n){
  __shared__ __align__(16) unsigned short Wlds[128*136];
  int t = threadIdx.x, lane = t & 63, w = t >> 6;
  int quad = lane >> 4, m = lane & 15;
  int rbase = blockIdx.x*64 + w*16;
  int rowA = rbase + m; if (rowA >= n) rowA = n - 1;
  bf16x8 a[4];
  load_a(X16 + (size_t)rowA*128, quad, a);
  stage_w(wtres, Wlds, t);
  f32x4 accR[8], accG[8];
  #pragma unroll
  for (int nt = 0; nt < 8; ++nt){
    accR[nt][0]=0.f; accR[nt][1]=0.f; accR[nt][2]=0.f; accR[nt][3]=0.f;
    accG[nt][0]=0.f; accG[nt][1]=0.f; accG[nt][2]=0.f; accG[nt][3]=0.f;
  }
  __syncthreads();
  mfma_regs(a, Wlds, lane, accR);
  __syncthreads();
  stage_w(wtgat, Wlds, t);
  __syncthreads();
  mfma_regs(a, Wlds, lane, accG);

  float asv[8], adv[8];
  #pragma unroll
  for (int nt = 0; nt < 8; ++nt){ asv[nt] = as_[nt*16 + m]; adv[nt] = ad_[nt*16 + m]; }
  #pragma unroll
  for (int reg = 0; reg < 4; ++reg){
    int row = rbase + quad*4 + reg;
    float pe[4], pd[4];
    #pragma unroll
    for (int h = 0; h < 4; ++h){
      pe[h] = accG[2*h][reg]*asv[2*h] + accG[2*h+1][reg]*asv[2*h+1];
      pd[h] = accG[2*h][reg]*adv[2*h] + accG[2*h+1][reg]*adv[2*h+1];
    }
    #pragma unroll
    for (int h = 0; h < 4; ++h){
      pe[h] += __shfl_xor(pe[h], 1); pe[h] += __shfl_xor(pe[h], 2);
      pe[h] += __shfl_xor(pe[h], 4); pe[h] += __shfl_xor(pe[h], 8);
      pd[h] += __shfl_xor(pd[h], 1); pd[h] += __shfl_xor(pd[h], 2);
      pd[h] += __shfl_xor(pd[h], 4); pd[h] += __shfl_xor(pd[h], 8);
    }
    if (m == 0 && row < n){
      #pragma unroll
      for (int h = 0; h < 4; ++h){ es[row*4 + h] = pe[h]; ed[row*4 + h] = pd[h]; }
    }
  }
  __syncthreads();
  epi_store16(accR, bres,    Wlds + w*2112, R16, rbase, lane, n);
  epi_store16(accG, nullptr, Wlds + w*2112, H16, rbase, lane, n);
}

// ---- SAGE dual GEMM: Y16 = bf16(Xa@Wa + bias + Xb@Wb), BN partials ----
__global__ __launch_bounds__(256) void k_mgemm2(const unsigned short* __restrict__ Xa,
    const unsigned short* __restrict__ wta, const unsigned short* __restrict__ Xb,
    const unsigned short* __restrict__ wtb, const float* __restrict__ bias,
    unsigned short* __restrict__ Y16, int n, float* __restrict__ bnpart){
  __shared__ __align__(16) unsigned short Wlds[128*136];
  __shared__ float wredS[4][128], wredQ[4][128];
  int t = threadIdx.x, lane = t & 63, w = t >> 6;
  int quad = lane >> 4, m = lane & 15;
  int rbase = blockIdx.x*64 + w*16;
  int rowA = rbase + m; if (rowA >= n) rowA = n - 1;
  bf16x8 aa[4], ab[4];
  load_a(Xa + (size_t)rowA*128, quad, aa);
  load_a(Xb + (size_t)rowA*128, quad, ab);
  stage_w(wta, Wlds, t);
  f32x4 acc[8];
  #pragma unroll
  for (int nt = 0; nt < 8; ++nt){ acc[nt][0]=0.f; acc[nt][1]=0.f; acc[nt][2]=0.f; acc[nt][3]=0.f; }
  __syncthreads();
  mfma_regs(aa, Wlds, lane, acc);
  __syncthreads();
  stage_w(wtb, Wlds, t);
  __syncthreads();
  mfma_regs(ab, Wlds, lane, acc);

  float colS[8], colQ[8];
  #pragma unroll
  for (int nt = 0; nt < 8; ++nt){
    float bv = bias[nt*16 + m];
    float s = 0.f, q = 0.f;
    #pragma unroll
    for (int reg = 0; reg < 4; ++reg){
      float o = acc[nt][reg] + bv;
      acc[nt][reg] = o;
      if (rbase + quad*4 + reg < n){ s += o; q += o*o; }
    }
    s += __shfl_xor(s, 16); s += __shfl_xor(s, 32);
    q += __shfl_xor(q, 16); q += __shfl_xor(q, 32);
    colS[nt] = s; colQ[nt] = q;
  }
  if (quad == 0){
    #pragma unroll
    for (int nt = 0; nt < 8; ++nt){
      wredS[w][nt*16 + m] = colS[nt];
      wredQ[w][nt*16 + m] = colQ[nt];
    }
  }
  __syncthreads();
  if (t < 128){
    float S = wredS[0][t] + wredS[1][t] + wredS[2][t] + wredS[3][t];
    float Q = wredQ[0][t] + wredQ[1][t] + wredQ[2][t] + wredQ[3][t];
    bnpart[(size_t)blockIdx.x*256 + t]       = S;
    bnpart[(size_t)blockIdx.x*256 + 128 + t] = Q;
  }
  epi_store16(acc, nullptr, Wlds + w*2112, Y16, rbase, lane, n);
}

__global__ void k_bnred(const float* __restrict__ part, int nblk,
                        float* __restrict__ sums){
  int g = blockIdx.x, t = threadIdx.x;
  int chunk = (nblk + 63) / 64;
  int b0 = g*chunk, b1 = min(nblk, b0 + chunk);
  float s = 0.f;
  for (int b = b0; b < b1; ++b) s += part[(size_t)b*256 + t];
  if (b0 < b1) atomicAdd(&sums[t], s);
}

// --------- GAT aggregation: one node/wave, hoisted-clamp inner loop ---------
__global__ __launch_bounds__(256) void k_gat(const uint4* __restrict__ h16,
    const float* __restrict__ es, const float* __restrict__ edv,
    const int* __restrict__ rowStart, const int* __restrict__ srcList,
    const float* __restrict__ bias, uint4* __restrict__ out16){
  int i = blockIdx.x*4 + (threadIdx.x >> 6);
  if (i >= N_NODES) return;
  int lane = threadIdx.x & 63;
  int sub = lane >> 4;
  int m   = lane & 15;
  int hd  = m >> 2;
  float edi = edv[i*4 + hd];
  float acc[8];
  #pragma unroll
  for (int j = 0; j < 8; ++j) acc[j] = 0.f;
  float z = 0.f;
  if (sub == 0){
    float ws = __expf(lrelu(es[i*4 + hd] + edi));
    uint4 u = h16[i*16 + m];
    float2 v0=bf2f2(u.x), v1=bf2f2(u.y), v2=bf2f2(u.z), v3=bf2f2(u.w);
    acc[0]=v0.x*ws; acc[1]=v0.y*ws; acc[2]=v1.x*ws; acc[3]=v1.y*ws;
    acc[4]=v2.x*ws; acc[5]=v2.y*ws; acc[6]=v3.x*ws; acc[7]=v3.y*ws;
    z = ws;
  }
  int k0 = rowStart[i], ke = rowStart[i + 1];
  int kfull = k0 + ((ke - k0) & ~7);
  int k = k0;
  for (; k < kfull; k += 8){
    int s0 = srcList[k + sub];
    int s1 = srcList[k + 4 + sub];
    uint4 u0 = h16[s0*16 + m];
    uint4 u1 = h16[s1*16 + m];
    float w0 = __expf(lrelu(es[s0*4 + hd] + edi));
    float w1 = __expf(lrelu(es[s1*4 + hd] + edi));
    z += w0 + w1;
    float2 a0=bf2f2(u0.x), a1=bf2f2(u0.y), a2=bf2f2(u0.z), a3=bf2f2(u0.w);
    float2 b0=bf2f2(u1.x), b1=bf2f2(u1.y), b2=bf2f2(u1.z), b3=bf2f2(u1.w);
    acc[0] += a0.x*w0 + b0.x*w1;  acc[1] += a0.y*w0 + b0.y*w1;
    acc[2] += a1.x*w0 + b1.x*w1;  acc[3] += a1.y*w0 + b1.y*w1;
    acc[4] += a2.x*w0 + b2.x*w1;  acc[5] += a2.y*w0 + b2.y*w1;
    acc[6] += a3.x*w0 + b3.x*w1;  acc[7] += a3.y*w0 + b3.y*w1;
  }
  if (k < ke){
    int e0 = k + sub, e1 = k + 4 + sub;
    int c0 = e0 < ke ? e0 : ke - 1;
    int c1 = e1 < ke ? e1 : ke - 1;
    int s0 = srcList[c0];
    int s1 = srcList[c1];
    uint4 u0 = h16[s0*16 + m];
    uint4 u1 = h16[s1*16 + m];
    float w0 = (e0 < ke) ? __expf(lrelu(es[s0*4 + hd] + edi)) : 0.f;
    float w1 = (e1 < ke) ? __expf(lrelu(es[s1*4 + hd] + edi)) : 0.f;
    z += w0 + w1;
    float2 a0=bf2f2(u0.x), a1=bf2f2(u0.y), a2=bf2f2(u0.z), a3=bf2f2(u0.w);
    float2 b0=bf2f2(u1.x), b1=bf2f2(u1.y), b2=bf2f2(u1.z), b3=bf2f2(u1.w);
    acc[0] += a0.x*w0 + b0.x*w1;  acc[1] += a0.y*w0 + b0.y*w1;
    acc[2] += a1.x*w0 + b1.x*w1;  acc[3] += a1.y*w0 + b1.y*w1;
    acc[4] += a2.x*w0 + b2.x*w1;  acc[5] += a2.y*w0 + b2.y*w1;
    acc[6] += a3.x*w0 + b3.x*w1;  acc[7] += a3.y*w0 + b3.y*w1;
  }
  #pragma unroll
  for (int j = 0; j < 8; ++j){
    acc[j] += __shfl_xor(acc[j], 16);
    acc[j] += __shfl_xor(acc[j], 32);
  }
  z += __shfl_xor(z, 16);
  z += __shfl_xor(z, 32);
  if (sub == 0){
    float inv = 1.f / z;
    float4 bv0 = *(const float4*)(bias + m*8);
    float4 bv1 = *(const float4*)(bias + m*8 + 4);
    uint4 pk;
    pk.x = f2bf(acc[0]*inv + bv0.x) | (f2bf(acc[1]*inv + bv0.y) << 16);
    pk.y = f2bf(acc[2]*inv + bv0.z) | (f2bf(acc[3]*inv + bv0.w) << 16);
    pk.z = f2bf(acc[4]*inv + bv1.x) | (f2bf(acc[5]*inv + bv1.y) << 16);
    pk.w = f2bf(acc[6]*inv + bv1.z) | (f2bf(acc[7]*inv + bv1.w) << 16);
    out16[i*16 + m] = pk;
  }
}

// ---------------- SAGE mean aggregation (hoisted clamp) ----------------
__global__ __launch_bounds__(256) void k_sage_mean(const uint4* __restrict__ h16,
    const int* __restrict__ rowStart, const int* __restrict__ srcList,
    uint4* __restrict__ out16){
  int i = blockIdx.x*4 + (threadIdx.x >> 6);
  if (i >= N_NODES) return;
  int lane = threadIdx.x & 63;
  int sub = lane >> 4;
  int m   = lane & 15;
  float acc[8];
  #pragma unroll
  for (int j = 0; j < 8; ++j) acc[j] = 0.f;
  int k0 = rowStart[i], ke = rowStart[i + 1];
  int kfull = k0 + ((ke - k0) & ~7);
  int k = k0;
  for (; k < kfull; k += 8){
    int s0 = srcList[k + sub];
    int s1 = srcList[k + 4 + sub];
    uint4 u0 = h16[s0*16 + m];
    uint4 u1 = h16[s1*16 + m];
    float2 a0=bf2f2(u0.x), a1=bf2f2(u0.y), a2=bf2f2(u0.z), a3=bf2f2(u0.w);
    float2 b0=bf2f2(u1.x), b1=bf2f2(u1.y), b2=bf2f2(u1.z), b3=bf2f2(u1.w);
    acc[0] += a0.x + b0.x;  acc[1] += a0.y + b0.y;
    acc[2] += a1.x + b1.x;  acc[3] += a1.y + b1.y;
    acc[4] += a2.x + b2.x;  acc[5] += a2.y + b2.y;
    acc[6] += a3.x + b3.x;  acc[7] += a3.y + b3.y;
  }
  if (k < ke){
    int e0 = k + sub, e1 = k + 4 + sub;
    int c0 = e0 < ke ? e0 : ke - 1;
    int c1 = e1 < ke ? e1 : ke - 1;
    int s0 = srcList[c0];
    int s1 = srcList[c1];
    uint4 u0 = h16[s0*16 + m];
    uint4 u1 = h16[s1*16 + m];
    float w0 = (e0 < ke) ? 1.f : 0.f;
    float w1 = (e1 < ke) ? 1.f : 0.f;
    float2 a0=bf2f2(u0.x), a1=bf2f2(u0.y), a2=bf2f2(u0.z), a3=bf2f2(u0.w);
    float2 b0=bf2f2(u1.x), b1=bf2f2(u1.y), b2=bf2f2(u1.z), b3=bf2f2(u1.w);
    acc[0] += a0.x*w0 + b0.x*w1;  acc[1] += a0.y*w0 + b0.y*w1;
    acc[2] += a1.x*w0 + b1.x*w1;  acc[3] += a1.y*w0 + b1.y*w1;
    acc[4] += a2.x*w0 + b2.x*w1;  acc[5] += a2.y*w0 + b2.y*w1;
    acc[6] += a3.x*w0 + b3.x*w1;  acc[7] += a3.y*w0 + b3.y*w1;
  }
  #pragma unroll
  for (int j = 0; j < 8; ++j){
    acc[j] += __shfl_xor(acc[j], 16);
    acc[j] += __shfl_xor(acc[j], 32);
  }
  if (sub == 0){
    int dg = ke - k0;
    float inv = 1.f / (float)(dg > 0 ? dg : 1);
    uint4 pk;
    pk.x = f2bf(acc[0]*inv) | (f2bf(acc[1]*inv) << 16);
    pk.y = f2bf(acc[2]*inv) | (f2bf(acc[3]*inv) << 16);
    pk.z = f2bf(acc[4]*inv) | (f2bf(acc[5]*inv) << 16);
    pk.w = f2bf(acc[6]*inv) | (f2bf(acc[7]*inv) << 16);
    out16[i*16 + m] = pk;
  }
}

// ---------------- BatchNorm stats from bf16 ----------------
__global__ __launch_bounds__(256) void k_bnstat(const unsigned int* __restrict__ x16,
                                                float* __restrict__ sums){
  int colu = threadIdx.x & 63;
  int ro   = threadIdx.x >> 6;
  float s0 = 0.f, s1 = 0.f, q0 = 0.f, q1 = 0.f;
  for (int r = blockIdx.x*4 + ro; r < N_NODES; r += gridDim.x*4){
    float2 v = bf2f2(x16[(size_t)r*64 + colu]);
    s0 += v.x; s1 += v.y; q0 += v.x*v.x; q1 += v.y*v.y;
  }
  __shared__ float rs0[256], rs1[256], rq0[256], rq1[256];
  int t = threadIdx.x;
  rs0[t] = s0; rs1[t] = s1; rq0[t] = q0; rq1[t] = q1;
  __syncthreads();
  if (t < 64){
    float S0 = rs0[t] + rs0[t+64] + rs0[t+128] + rs0[t+192];
    float S1 = rs1[t] + rs1[t+64] + rs1[t+128] + rs1[t+192];
    float Q0 = rq0[t] + rq0[t+64] + rq0[t+128] + rq0[t+192];
    float Q1 = rq1[t] + rq1[t+64] + rq1[t+128] + rq1[t+192];
    atomicAdd(&sums[2*t],       S0);
    atomicAdd(&sums[2*t + 1],   S1);
    atomicAdd(&sums[128 + 2*t],     Q0);
    atomicAdd(&sums[128 + 2*t + 1], Q1);
  }
}

// --------- BN apply (+opt bf16 residual) + lrelu; bf16 in/out ---------
__global__ void k_bnapply(const unsigned int* __restrict__ x16,
    const float* __restrict__ sums, const float* __restrict__ g,
    const float* __restrict__ b, const unsigned int* __restrict__ res16,
    unsigned int* __restrict__ y16){
  int f = blockIdx.x*256 + threadIdx.x;
  if (f >= N_NODES*32) return;
  int c = (f & 31) * 4;
  uint2 u = *(const uint2*)(x16 + (size_t)f*2);
  float2 vA = bf2f2(u.x), vB = bf2f2(u.y);
  float vv[4] = {vA.x, vA.y, vB.x, vB.y};
  float rr[4] = {0.f, 0.f, 0.f, 0.f};
  if (res16){
    uint2 ur = *(const uint2*)(res16 + (size_t)f*2);
    float2 rA = bf2f2(ur.x), rB = bf2f2(ur.y);
    rr[0]=rA.x; rr[1]=rA.y; rr[2]=rB.x; rr[3]=rB.y;
  }
  float o[4];
  const float invn = 1.f / (float)N_NODES;
  #pragma unroll
  for (int j = 0; j < 4; ++j){
    int cc = c + j;
    float mu  = sums[cc] * invn;
    float var = sums[128 + cc] * invn - mu*mu;
    float rs  = rsqrtf(var + EPSV);
    o[j] = lrelu((vv[j] - mu)*rs*g[cc] + b[cc] + rr[j]);
  }
  uint2 pk;
  pk.x = f2bf(o[0]) | (f2bf(o[1]) << 16);
  pk.y = f2bf(o[2]) | (f2bf(o[3]) << 16);
  *(uint2*)(y16 + (size_t)f*2) = pk;
}

// -------- global mean pool + fused FC (last block does FC) --------
__global__ __launch_bounds__(256) void k_pool_fc(const unsigned int* __restrict__ h16,
    const int* __restrict__ batch, float* __restrict__ pooled,
    float* __restrict__ cnt, int* __restrict__ pctr,
    const float* __restrict__ W, const float* __restrict__ bfc,
    float* __restrict__ out){
  int colu = threadIdx.x & 63;
  int ro   = threadIdx.x >> 6;
  int base = blockIdx.x * 128;
  int g_cur = -1; float a0 = 0.f, a1 = 0.f, cacc = 0.f;
  for (int ii = 0; ii < 32; ++ii){
    int r = base + ro + ii*4;
    if (r >= N_NODES) break;
    int g = batch[r];
    if (g != g_cur){
      if (g_cur >= 0){
        atomicAdd(&pooled[g_cur*D + 2*colu],     a0);
        atomicAdd(&pooled[g_cur*D + 2*colu + 1], a1);
        if (colu == 0) atomicAdd(&cnt[g_cur], cacc);
      }
      a0 = 0.f; a1 = 0.f; cacc = 0.f; g_cur = g;
    }
    float2 v = bf2f2(h16[(size_t)r*64 + colu]);
    a0 += v.x; a1 += v.y; cacc += 1.f;
  }
  if (g_cur >= 0){
    atomicAdd(&pooled[g_cur*D + 2*colu],     a0);
    atomicAdd(&pooled[g_cur*D + 2*colu + 1], a1);
    if (colu == 0) atomicAdd(&cnt[g_cur], cacc);
  }
  // ticket: last block computes FC
  __threadfence();
  __shared__ int isLast;
  if (threadIdx.x == 0)
    isLast = (atomicAdd(pctr, 1) == (int)gridDim.x - 1);
  __syncthreads();
  if (isLast){
    __threadfence();
    for (int idx = threadIdx.x; idx < GR*64; idx += 256){
      int g = idx >> 6, o = idx & 63;
      const float* p = pooled + g*D;
      float s = 0.f;
      for (int c2 = 0; c2 < D; ++c2) s += p[c2] * W[c2*64 + o];
      float inv = 1.f / fmaxf(cnt[g], 1.f);
      out[idx] = s*inv + bfc[o];
    }
  }
}

extern "C" void kernel_launch(void* const* d_in, const int* in_sizes, int n_in,
                              void* d_out, int out_size, void* d_ws, size_t ws_size,
                              hipStream_t stream){
  (void)in_sizes; (void)n_in; (void)out_size; (void)ws_size;
  const float* x       = (const float*)d_in[0];
  const int*   ei      = (const int*)  d_in[1];
  const int*   batch   = (const int*)  d_in[2];
  const float* gat1_W  = (const float*)d_in[3];
  const float* gat1_as = (const float*)d_in[4];
  const float* gat1_ad = (const float*)d_in[5];
  const float* gat1_b  = (const float*)d_in[6];
  const float* gat2_W  = (const float*)d_in[7];
  const float* gat2_as = (const float*)d_in[8];
  const float* gat2_ad = (const float*)d_in[9];
  const float* gat2_b  = (const float*)d_in[10];
  const float* s3_Wl   = (const float*)d_in[11];
  const float* s3_bl   = (const float*)d_in[12];
  const float* s3_Wr   = (const float*)d_in[13];
  const float* s4_Wl   = (const float*)d_in[14];
  const float* s4_bl   = (const float*)d_in[15];
  const float* s4_Wr   = (const float*)d_in[16];
  const float* s5_Wl   = (const float*)d_in[17];
  const float* s5_bl   = (const float*)d_in[18];
  const float* s5_Wr   = (const float*)d_in[19];
  const float* bn1_g = (const float*)d_in[20]; const float* bn1_b = (const float*)d_in[21];
  const float* bn2_g = (const float*)d_in[22]; const float* bn2_b = (const float*)d_in[23];
  const float* bn3_g = (const float*)d_in[24]; const float* bn3_b = (const float*)d_in[25];
  const float* bn4_g = (const float*)d_in[26]; const float* bn4_b = (const float*)d_in[27];
  const float* bn5_g = (const float*)d_in[28]; const float* bn5_b = (const float*)d_in[29];
  const float* res1_W = (const float*)d_in[30]; const float* res1_b = (const float*)d_in[31];
  const float* res2_W = (const float*)d_in[32]; const float* res2_b = (const float*)d_in[33];
  const float* fc_W   = (const float*)d_in[34]; const float* fc_b   = (const float*)d_in[35];
  float* out = (float*)d_out;

  char* ws = (char*)d_ws;
  size_t off = 0;
  auto alloc = [&](size_t bytes) -> void* {
    void* p = ws + off; off += (bytes + 255) & ~(size_t)255; return p;
  };
  const int mgrid = (N_NODES + 63) / 64;
  int*   rowStart = (int*)  alloc((N_NODES + 1) * 4);
  int*   rank     = (int*)  alloc((size_t)N_EDGES * 4);
  int*   srcList  = (int*)  alloc((size_t)N_EDGES * 4);
  int*   bsum     = (int*)  alloc(256 * 4);
  // ---- contiguous zero region: deg | bnsums | pooled | cnt | pctr ----
  size_t zoff0 = off;
  int*   deg      = (int*)  alloc((size_t)N_NODES * 4);
  float* bnsums   = (float*)alloc(5 * 256 * 4);
  float* pooled   = (float*)alloc(GR * D * 4);
  float* cnt      = (float*)alloc(64 * 4);
  int*   pctr     = (int*)  alloc(4);
  size_t zbytes = off - zoff0;
  float* es       = (float*)alloc((size_t)N_NODES * 4 * 4);
  float* edv      = (float*)alloc((size_t)N_NODES * 4 * 4);
  float* bnpart   = (float*)alloc((size_t)mgrid * 256 * 4);
  unsigned short* Wt16 = (unsigned short*)alloc(10 * 16384 * 2);
  unsigned short* HX   = (unsigned short*)alloc((size_t)N_NODES * D * 2);
  unsigned short* H16a = (unsigned short*)alloc((size_t)N_NODES * D * 2);
  unsigned short* HO   = (unsigned short*)alloc((size_t)N_NODES * D * 2);
  unsigned short* HR   = (unsigned short*)alloc((size_t)N_NODES * D * 2);

  const int* srcE = ei;
  const int* dstE = ei + N_EDGES;
  const int nb = (N_NODES + 255) / 256;
  const int egrid = (N_EDGES + 255) / 256;
  const int agrid = (N_NODES + 3) / 4;
  const int bgrid = (N_NODES*32 + 255) / 256;
  const int pgrid = (N_NODES + 127) / 128;

  // single zeroing memset + CSR build
  hipMemsetAsync(ws + zoff0, 0, zbytes, stream);
  k_countrank<<<egrid, 256, 0, stream>>>(dstE, deg, rank);
  k_scan1<<<nb, 256, 0, stream>>>(deg, bsum);
  k_scan2b<<<1, 256, 0, stream>>>(bsum, nb, rowStart);
  k_scan3<<<nb, 256, 0, stream>>>(deg, bsum, rowStart);
  k_scatter<<<egrid, 256, 0, stream>>>(srcE, dstE, rank, rowStart, srcList);

  // fused casts (weights + x)
  WPack wp;
  wp.w[0]=res1_W; wp.w[1]=gat1_W; wp.w[2]=res2_W; wp.w[3]=gat2_W;
  wp.w[4]=s3_Wl;  wp.w[5]=s3_Wr;  wp.w[6]=s4_Wl;  wp.w[7]=s4_Wr;
  wp.w[8]=s5_Wl;  wp.w[9]=s5_Wr;
  k_casts<<<640 + bgrid, 256, 0, stream>>>(wp, Wt16, x, HX);

  // ---- layer 1 (GAT) ----
  k_mgemm_dual<<<mgrid, 256, 0, stream>>>(HX, Wt16 + 0*16384, Wt16 + 1*16384,
                                          res1_b, gat1_as, gat1_ad,
                                          HR, H16a, es, edv, N_NODES);
  k_gat<<<agrid, 256, 0, stream>>>((const uint4*)H16a, es, edv, rowStart,
                                   srcList, gat1_b, (uint4*)HO);
  k_bnstat<<<256, 256, 0, stream>>>((const unsigned int*)HO, bnsums);
  k_bnapply<<<bgrid, 256, 0, stream>>>((const unsigned int*)HO, bnsums, bn1_g, bn1_b,
                                       (const unsigned int*)HR, (unsigned int*)H16a);

  // ---- layer 2 (GAT) ----
  k_mgemm_dual<<<mgrid, 256, 0, stream>>>(H16a, Wt16 + 2*16384, Wt16 + 3*16384,
                                          res2_b, gat2_as, gat2_ad,
                                          HR, HX, es, edv, N_NODES);
  k_gat<<<agrid, 256, 0, stream>>>((const uint4*)HX, es, edv, rowStart,
                                   srcList, gat2_b, (uint4*)HO);
  k_bnstat<<<256, 256, 0, stream>>>((const unsigned int*)HO, bnsums + 256);
  k_bnapply<<<bgrid, 256, 0, stream>>>((const unsigned int*)HO, bnsums + 256, bn2_g, bn2_b,
                                       (const unsigned int*)HR, (unsigned int*)H16a);

  // ---- layer 3 (SAGE) ----
  k_sage_mean<<<agrid, 256, 0, stream>>>((const uint4*)H16a, rowStart, srcList,
                                         (uint4*)HX);
  k_mgemm2<<<mgrid, 256, 0, stream>>>(HX, Wt16 + 4*16384, H16a, Wt16 + 5*16384,
                                      s3_bl, HO, N_NODES, bnpart);
  k_bnred<<<64, 256, 0, stream>>>(bnpart, mgrid, bnsums + 512);
  k_bnapply<<<bgrid, 256, 0, stream>>>((const unsigned int*)HO, bnsums + 512, bn3_g, bn3_b,
                                       nullptr, (unsigned int*)H16a);

  // ---- layer 4 (SAGE) ----
  k_sage_mean<<<agrid, 256, 0, stream>>>((const uint4*)H16a, rowStart, srcList,
                                         (uint4*)HX);
  k_mgemm2<<<mgrid, 256, 0, stream>>>(HX, Wt16 + 6*16384, H16a, Wt16 + 7*16384,
                                      s4_bl, HO, N_NODES, bnpart);
  k_bnred<<<64, 256, 0, stream>>>(bnpart, mgrid, bnsums + 768);
  k_bnapply<<<bgrid, 256, 0, stream>>>((const unsigned int*)HO, bnsums + 768, bn4_g, bn4_b,
                                       nullptr, (unsigned int*)H16a);

  // ---- layer 5 (SAGE) ----
  k_sage_mean<<<agrid, 256, 0, stream>>>((const uint4*)H16a, rowStart, srcList,
                                         (uint4*)HX);
  k_mgemm2<<<mgrid, 256, 0, stream>>>(HX, Wt16 + 8*16384, H16a, Wt16 + 9*16384,
                                      s5_bl, HO, N_NODES, bnpart);
  k_bnred<<<64, 256, 0, stream>>>(bnpart, mgrid, bnsums + 1024);
  k_bnapply<<<bgrid, 256, 0, stream>>>((const unsigned int*)HO, bnsums + 1024, bn5_g, bn5_b,
                                       nullptr, (unsigned int*)H16a);

  // ---- pool + fused fc ----
  k_pool_fc<<<pgrid, 256, 0, stream>>>((const unsigned int*)H16a, batch, pooled, cnt,
                                       pctr, fc_W, fc_b, out);
}

// Round 11
// 603.904 us; speedup vs baseline: 1.0750x; 1.0750x over previous
//
#include <hip/hip_runtime.h>
#include <math.h>
#include <stdint.h>

#define N_NODES 50000
#define N_EDGES 800000
#define D 128
#define GR 50
#define EPSV 1e-5f

typedef __attribute__((ext_vector_type(8))) short bf16x8;
typedef __attribute__((ext_vector_type(4))) float f32x4;

__device__ __forceinline__ float lrelu(float v){ return v > 0.f ? v : 0.2f*v; }

__device__ __forceinline__ unsigned int f2bf(float f){
  union { float f; uint32_t i; } v; v.f = f;
  uint32_t r = v.i + 0x7fffu + ((v.i >> 16) & 1u);
  return r >> 16;
}
__device__ __forceinline__ float2 bf2f2(uint32_t u){
  union { uint32_t i; float f; } a, b;
  a.i = u << 16;
  b.i = u & 0xffff0000u;
  return make_float2(a.f, b.f);
}

// ---------------- CSR build (one atomic pass) ----------------
__global__ void k_countrank(const int* __restrict__ dst, int* __restrict__ deg,
                            int* __restrict__ rank){
  int e = blockIdx.x*256 + threadIdx.x;
  if (e < N_EDGES) rank[e] = atomicAdd(&deg[dst[e]], 1);
}
__global__ void k_scan1(const int* __restrict__ deg, int* __restrict__ bsum){
  __shared__ int s[256];
  int i = blockIdx.x*256 + threadIdx.x;
  int v = (i < N_NODES) ? deg[i] : 0;
  s[threadIdx.x] = v; __syncthreads();
  for (int off = 128; off > 0; off >>= 1){
    if (threadIdx.x < off) s[threadIdx.x] += s[threadIdx.x + off];
    __syncthreads();
  }
  if (threadIdx.x == 0) bsum[blockIdx.x] = s[0];
}
__global__ void k_scan2b(int* __restrict__ bsum, int nb, int* __restrict__ rowStart){
  __shared__ int s[256];
  int t = threadIdx.x;
  int v = (t < nb) ? bsum[t] : 0;
  s[t] = v; __syncthreads();
  for (int off = 1; off < 256; off <<= 1){
    int xv = (t >= off) ? s[t - off] : 0;
    __syncthreads();
    s[t] += xv;
    __syncthreads();
  }
  if (t < nb) bsum[t] = s[t] - v;
  if (t == 255) rowStart[N_NODES] = s[255];
}
__global__ void k_scan3(const int* __restrict__ deg, const int* __restrict__ bsum,
                        int* __restrict__ rowStart){
  __shared__ int s[256];
  int i = blockIdx.x*256 + threadIdx.x;
  int v = (i < N_NODES) ? deg[i] : 0;
  s[threadIdx.x] = v; __syncthreads();
  for (int off = 1; off < 256; off <<= 1){
    int xv = (threadIdx.x >= off) ? s[threadIdx.x - off] : 0;
    __syncthreads();
    s[threadIdx.x] += xv;
    __syncthreads();
  }
  if (i < N_NODES) rowStart[i] = bsum[blockIdx.x] + s[threadIdx.x] - v;
}
__global__ void k_scatter(const int* __restrict__ src, const int* __restrict__ dst,
                          const int* __restrict__ rank, const int* __restrict__ rowStart,
                          int* __restrict__ srcList){
  int e = blockIdx.x*256 + threadIdx.x;
  if (e < N_EDGES)
    srcList[rowStart[dst[e]] + rank[e]] = src[e];
}

// ---------------- fused casts: weights (640 blocks) + x (rest) ----------------
struct WPack { const float* w[10]; };
__global__ void k_casts(WPack p, unsigned short* __restrict__ wt,
                        const float* __restrict__ x, unsigned short* __restrict__ x16){
  int b = blockIdx.x;
  if (b < 640){
    int mat = b >> 6;
    int local = (b & 63)*256 + threadIdx.x;
    int c = local >> 7, k = local & 127;
    wt[(size_t)mat*16384 + c*128 + k] = (unsigned short)f2bf(p.w[mat][k*128 + c]);
  } else {
    int idx = (b - 640)*256 + threadIdx.x;
    if (idx >= N_NODES*32) return;
    float4 v = *(const float4*)(x + (size_t)idx*4);
    uint2 pk;
    pk.x = f2bf(v.x) | (f2bf(v.y) << 16);
    pk.y = f2bf(v.z) | (f2bf(v.w) << 16);
    *(uint2*)(x16 + (size_t)idx*4) = pk;
  }
}

// ======================= MFMA GEMM family =======================
__device__ __forceinline__ void stage_w(const unsigned short* __restrict__ wt,
                                        unsigned short* __restrict__ lds, int t){
  #pragma unroll
  for (int i = 0; i < 8; ++i){
    int ch = i*256 + t;
    int col = ch >> 4, kc = ch & 15;
    *(uint4*)(&lds[col*136 + kc*8]) = *(const uint4*)(wt + ((size_t)col << 7) + (kc << 3));
  }
}

__device__ __forceinline__ void load_a(const unsigned short* __restrict__ xrow,
                                       int quad, bf16x8 a[4]){
  #pragma unroll
  for (int ks = 0; ks < 4; ++ks)
    a[ks] = *(const bf16x8*)(xrow + ks*32 + quad*8);
}

__device__ __forceinline__ void mfma_regs(const bf16x8 a[4],
                                          const unsigned short* __restrict__ lds,
                                          int lane, f32x4 acc[8]){
  int quad = lane >> 4, m = lane & 15;
  #pragma unroll
  for (int ks = 0; ks < 4; ++ks){
    #pragma unroll
    for (int nt = 0; nt < 8; ++nt){
      bf16x8 b = *(const bf16x8*)(&lds[(nt*16 + m)*136 + ks*32 + quad*8]);
      acc[nt] = __builtin_amdgcn_mfma_f32_16x16x32_bf16(a[ks], b, acc[nt], 0, 0, 0);
    }
  }
}

__device__ __forceinline__ void epi_store16(f32x4 acc[8], const float* bias,
    unsigned short* __restrict__ ldsw, unsigned short* __restrict__ Y16,
    int rbase, int lane, int n){
  int quad = lane >> 4, m = lane & 15;
  #pragma unroll
  for (int nt = 0; nt < 8; ++nt){
    int col = nt*16 + m;
    float bv = bias ? bias[col] : 0.f;
    #pragma unroll
    for (int reg = 0; reg < 4; ++reg)
      ldsw[(quad*4 + reg)*132 + col] = (unsigned short)f2bf(acc[nt][reg] + bv);
  }
  int r = lane >> 2, seg = lane & 3;
  int grow = rbase + r;
  if (grow < n){
    unsigned short* gp = Y16 + (size_t)grow*128 + seg*32;
    #pragma unroll
    for (int j = 0; j < 4; ++j)
      *(uint4*)(gp + j*8) = *(const uint4*)(&ldsw[r*132 + seg*32 + j*8]);
  }
}

// ---- GAT-layer dual GEMM: R16 = bf16(X@Wres + bres); H16 = bf16(X@Wgat); es/ed
__global__ __launch_bounds__(256) void k_mgemm_dual(const unsigned short* __restrict__ X16,
    const unsigned short* __restrict__ wtres, const unsigned short* __restrict__ wtgat,
    const float* __restrict__ bres, const float* __restrict__ as_,
    const float* __restrict__ ad_, unsigned short* __restrict__ R16,
    unsigned short* __restrict__ H16, float* __restrict__ es, float* __restrict__ ed,
    int n){
  __shared__ __align__(16) unsigned short Wlds[128*136];
  int t = threadIdx.x, lane = t & 63, w = t >> 6;
  int quad = lane >> 4, m = lane & 15;
  int rbase = blockIdx.x*64 + w*16;
  int rowA = rbase + m; if (rowA >= n) rowA = n - 1;
  bf16x8 a[4];
  load_a(X16 + (size_t)rowA*128, quad, a);
  stage_w(wtres, Wlds, t);
  f32x4 accR[8], accG[8];
  #pragma unroll
  for (int nt = 0; nt < 8; ++nt){
    accR[nt][0]=0.f; accR[nt][1]=0.f; accR[nt][2]=0.f; accR[nt][3]=0.f;
    accG[nt][0]=0.f; accG[nt][1]=0.f; accG[nt][2]=0.f; accG[nt][3]=0.f;
  }
  __syncthreads();
  mfma_regs(a, Wlds, lane, accR);
  __syncthreads();
  stage_w(wtgat, Wlds, t);
  __syncthreads();
  mfma_regs(a, Wlds, lane, accG);

  float asv[8], adv[8];
  #pragma unroll
  for (int nt = 0; nt < 8; ++nt){ asv[nt] = as_[nt*16 + m]; adv[nt] = ad_[nt*16 + m]; }
  #pragma unroll
  for (int reg = 0; reg < 4; ++reg){
    int row = rbase + quad*4 + reg;
    float pe[4], pd[4];
    #pragma unroll
    for (int h = 0; h < 4; ++h){
      pe[h] = accG[2*h][reg]*asv[2*h] + accG[2*h+1][reg]*asv[2*h+1];
      pd[h] = accG[2*h][reg]*adv[2*h] + accG[2*h+1][reg]*adv[2*h+1];
    }
    #pragma unroll
    for (int h = 0; h < 4; ++h){
      pe[h] += __shfl_xor(pe[h], 1); pe[h] += __shfl_xor(pe[h], 2);
      pe[h] += __shfl_xor(pe[h], 4); pe[h] += __shfl_xor(pe[h], 8);
      pd[h] += __shfl_xor(pd[h], 1); pd[h] += __shfl_xor(pd[h], 2);
      pd[h] += __shfl_xor(pd[h], 4); pd[h] += __shfl_xor(pd[h], 8);
    }
    if (m == 0 && row < n){
      #pragma unroll
      for (int h = 0; h < 4; ++h){ es[row*4 + h] = pe[h]; ed[row*4 + h] = pd[h]; }
    }
  }
  __syncthreads();
  epi_store16(accR, bres,    Wlds + w*2112, R16, rbase, lane, n);
  epi_store16(accG, nullptr, Wlds + w*2112, H16, rbase, lane, n);
}

// ---- SAGE dual GEMM: Y16 = bf16(Xa@Wa + bias + Xb@Wb), BN partials ----
__global__ __launch_bounds__(256) void k_mgemm2(const unsigned short* __restrict__ Xa,
    const unsigned short* __restrict__ wta, const unsigned short* __restrict__ Xb,
    const unsigned short* __restrict__ wtb, const float* __restrict__ bias,
    unsigned short* __restrict__ Y16, int n, float* __restrict__ bnpart){
  __shared__ __align__(16) unsigned short Wlds[128*136];
  __shared__ float wredS[4][128], wredQ[4][128];
  int t = threadIdx.x, lane = t & 63, w = t >> 6;
  int quad = lane >> 4, m = lane & 15;
  int rbase = blockIdx.x*64 + w*16;
  int rowA = rbase + m; if (rowA >= n) rowA = n - 1;
  bf16x8 aa[4], ab[4];
  load_a(Xa + (size_t)rowA*128, quad, aa);
  load_a(Xb + (size_t)rowA*128, quad, ab);
  stage_w(wta, Wlds, t);
  f32x4 acc[8];
  #pragma unroll
  for (int nt = 0; nt < 8; ++nt){ acc[nt][0]=0.f; acc[nt][1]=0.f; acc[nt][2]=0.f; acc[nt][3]=0.f; }
  __syncthreads();
  mfma_regs(aa, Wlds, lane, acc);
  __syncthreads();
  stage_w(wtb, Wlds, t);
  __syncthreads();
  mfma_regs(ab, Wlds, lane, acc);

  float colS[8], colQ[8];
  #pragma unroll
  for (int nt = 0; nt < 8; ++nt){
    float bv = bias[nt*16 + m];
    float s = 0.f, q = 0.f;
    #pragma unroll
    for (int reg = 0; reg < 4; ++reg){
      float o = acc[nt][reg] + bv;
      acc[nt][reg] = o;
      if (rbase + quad*4 + reg < n){ s += o; q += o*o; }
    }
    s += __shfl_xor(s, 16); s += __shfl_xor(s, 32);
    q += __shfl_xor(q, 16); q += __shfl_xor(q, 32);
    colS[nt] = s; colQ[nt] = q;
  }
  if (quad == 0){
    #pragma unroll
    for (int nt = 0; nt < 8; ++nt){
      wredS[w][nt*16 + m] = colS[nt];
      wredQ[w][nt*16 + m] = colQ[nt];
    }
  }
  __syncthreads();
  if (t < 128){
    float S = wredS[0][t] + wredS[1][t] + wredS[2][t] + wredS[3][t];
    float Q = wredQ[0][t] + wredQ[1][t] + wredQ[2][t] + wredQ[3][t];
    bnpart[(size_t)blockIdx.x*256 + t]       = S;
    bnpart[(size_t)blockIdx.x*256 + 128 + t] = Q;
  }
  epi_store16(acc, nullptr, Wlds + w*2112, Y16, rbase, lane, n);
}

__global__ void k_bnred(const float* __restrict__ part, int nblk,
                        float* __restrict__ sums){
  int g = blockIdx.x, t = threadIdx.x;
  int chunk = (nblk + 63) / 64;
  int b0 = g*chunk, b1 = min(nblk, b0 + chunk);
  float s = 0.f;
  for (int b = b0; b < b1; ++b) s += part[(size_t)b*256 + t];
  if (b0 < b1) atomicAdd(&sums[t], s);
}

// --------- GAT aggregation: one node/wave, hoisted-clamp inner loop ---------
__global__ __launch_bounds__(256) void k_gat(const uint4* __restrict__ h16,
    const float* __restrict__ es, const float* __restrict__ edv,
    const int* __restrict__ rowStart, const int* __restrict__ srcList,
    const float* __restrict__ bias, uint4* __restrict__ out16){
  int i = blockIdx.x*4 + (threadIdx.x >> 6);
  if (i >= N_NODES) return;
  int lane = threadIdx.x & 63;
  int sub = lane >> 4;
  int m   = lane & 15;
  int hd  = m >> 2;
  float edi = edv[i*4 + hd];
  float acc[8];
  #pragma unroll
  for (int j = 0; j < 8; ++j) acc[j] = 0.f;
  float z = 0.f;
  if (sub == 0){
    float ws = __expf(lrelu(es[i*4 + hd] + edi));
    uint4 u = h16[i*16 + m];
    float2 v0=bf2f2(u.x), v1=bf2f2(u.y), v2=bf2f2(u.z), v3=bf2f2(u.w);
    acc[0]=v0.x*ws; acc[1]=v0.y*ws; acc[2]=v1.x*ws; acc[3]=v1.y*ws;
    acc[4]=v2.x*ws; acc[5]=v2.y*ws; acc[6]=v3.x*ws; acc[7]=v3.y*ws;
    z = ws;
  }
  int k0 = rowStart[i], ke = rowStart[i + 1];
  int kfull = k0 + ((ke - k0) & ~7);
  int k = k0;
  for (; k < kfull; k += 8){
    int s0 = srcList[k + sub];
    int s1 = srcList[k + 4 + sub];
    uint4 u0 = h16[s0*16 + m];
    uint4 u1 = h16[s1*16 + m];
    float w0 = __expf(lrelu(es[s0*4 + hd] + edi));
    float w1 = __expf(lrelu(es[s1*4 + hd] + edi));
    z += w0 + w1;
    float2 a0=bf2f2(u0.x), a1=bf2f2(u0.y), a2=bf2f2(u0.z), a3=bf2f2(u0.w);
    float2 b0=bf2f2(u1.x), b1=bf2f2(u1.y), b2=bf2f2(u1.z), b3=bf2f2(u1.w);
    acc[0] += a0.x*w0 + b0.x*w1;  acc[1] += a0.y*w0 + b0.y*w1;
    acc[2] += a1.x*w0 + b1.x*w1;  acc[3] += a1.y*w0 + b1.y*w1;
    acc[4] += a2.x*w0 + b2.x*w1;  acc[5] += a2.y*w0 + b2.y*w1;
    acc[6] += a3.x*w0 + b3.x*w1;  acc[7] += a3.y*w0 + b3.y*w1;
  }
  if (k < ke){
    int e0 = k + sub, e1 = k + 4 + sub;
    int c0 = e0 < ke ? e0 : ke - 1;
    int c1 = e1 < ke ? e1 : ke - 1;
    int s0 = srcList[c0];
    int s1 = srcList[c1];
    uint4 u0 = h16[s0*16 + m];
    uint4 u1 = h16[s1*16 + m];
    float w0 = (e0 < ke) ? __expf(lrelu(es[s0*4 + hd] + edi)) : 0.f;
    float w1 = (e1 < ke) ? __expf(lrelu(es[s1*4 + hd] + edi)) : 0.f;
    z += w0 + w1;
    float2 a0=bf2f2(u0.x), a1=bf2f2(u0.y), a2=bf2f2(u0.z), a3=bf2f2(u0.w);
    float2 b0=bf2f2(u1.x), b1=bf2f2(u1.y), b2=bf2f2(u1.z), b3=bf2f2(u1.w);
    acc[0] += a0.x*w0 + b0.x*w1;  acc[1] += a0.y*w0 + b0.y*w1;
    acc[2] += a1.x*w0 + b1.x*w1;  acc[3] += a1.y*w0 + b1.y*w1;
    acc[4] += a2.x*w0 + b2.x*w1;  acc[5] += a2.y*w0 + b2.y*w1;
    acc[6] += a3.x*w0 + b3.x*w1;  acc[7] += a3.y*w0 + b3.y*w1;
  }
  #pragma unroll
  for (int j = 0; j < 8; ++j){
    acc[j] += __shfl_xor(acc[j], 16);
    acc[j] += __shfl_xor(acc[j], 32);
  }
  z += __shfl_xor(z, 16);
  z += __shfl_xor(z, 32);
  if (sub == 0){
    float inv = 1.f / z;
    float4 bv0 = *(const float4*)(bias + m*8);
    float4 bv1 = *(const float4*)(bias + m*8 + 4);
    uint4 pk;
    pk.x = f2bf(acc[0]*inv + bv0.x) | (f2bf(acc[1]*inv + bv0.y) << 16);
    pk.y = f2bf(acc[2]*inv + bv0.z) | (f2bf(acc[3]*inv + bv0.w) << 16);
    pk.z = f2bf(acc[4]*inv + bv1.x) | (f2bf(acc[5]*inv + bv1.y) << 16);
    pk.w = f2bf(acc[6]*inv + bv1.z) | (f2bf(acc[7]*inv + bv1.w) << 16);
    out16[i*16 + m] = pk;
  }
}

// ---------------- SAGE mean aggregation (hoisted clamp) ----------------
__global__ __launch_bounds__(256) void k_sage_mean(const uint4* __restrict__ h16,
    const int* __restrict__ rowStart, const int* __restrict__ srcList,
    uint4* __restrict__ out16){
  int i = blockIdx.x*4 + (threadIdx.x >> 6);
  if (i >= N_NODES) return;
  int lane = threadIdx.x & 63;
  int sub = lane >> 4;
  int m   = lane & 15;
  float acc[8];
  #pragma unroll
  for (int j = 0; j < 8; ++j) acc[j] = 0.f;
  int k0 = rowStart[i], ke = rowStart[i + 1];
  int kfull = k0 + ((ke - k0) & ~7);
  int k = k0;
  for (; k < kfull; k += 8){
    int s0 = srcList[k + sub];
    int s1 = srcList[k + 4 + sub];
    uint4 u0 = h16[s0*16 + m];
    uint4 u1 = h16[s1*16 + m];
    float2 a0=bf2f2(u0.x), a1=bf2f2(u0.y), a2=bf2f2(u0.z), a3=bf2f2(u0.w);
    float2 b0=bf2f2(u1.x), b1=bf2f2(u1.y), b2=bf2f2(u1.z), b3=bf2f2(u1.w);
    acc[0] += a0.x + b0.x;  acc[1] += a0.y + b0.y;
    acc[2] += a1.x + b1.x;  acc[3] += a1.y + b1.y;
    acc[4] += a2.x + b2.x;  acc[5] += a2.y + b2.y;
    acc[6] += a3.x + b3.x;  acc[7] += a3.y + b3.y;
  }
  if (k < ke){
    int e0 = k + sub, e1 = k + 4 + sub;
    int c0 = e0 < ke ? e0 : ke - 1;
    int c1 = e1 < ke ? e1 : ke - 1;
    int s0 = srcList[c0];
    int s1 = srcList[c1];
    uint4 u0 = h16[s0*16 + m];
    uint4 u1 = h16[s1*16 + m];
    float w0 = (e0 < ke) ? 1.f : 0.f;
    float w1 = (e1 < ke) ? 1.f : 0.f;
    float2 a0=bf2f2(u0.x), a1=bf2f2(u0.y), a2=bf2f2(u0.z), a3=bf2f2(u0.w);
    float2 b0=bf2f2(u1.x), b1=bf2f2(u1.y), b2=bf2f2(u1.z), b3=bf2f2(u1.w);
    acc[0] += a0.x*w0 + b0.x*w1;  acc[1] += a0.y*w0 + b0.y*w1;
    acc[2] += a1.x*w0 + b1.x*w1;  acc[3] += a1.y*w0 + b1.y*w1;
    acc[4] += a2.x*w0 + b2.x*w1;  acc[5] += a2.y*w0 + b2.y*w1;
    acc[6] += a3.x*w0 + b3.x*w1;  acc[7] += a3.y*w0 + b3.y*w1;
  }
  #pragma unroll
  for (int j = 0; j < 8; ++j){
    acc[j] += __shfl_xor(acc[j], 16);
    acc[j] += __shfl_xor(acc[j], 32);
  }
  if (sub == 0){
    int dg = ke - k0;
    float inv = 1.f / (float)(dg > 0 ? dg : 1);
    uint4 pk;
    pk.x = f2bf(acc[0]*inv) | (f2bf(acc[1]*inv) << 16);
    pk.y = f2bf(acc[2]*inv) | (f2bf(acc[3]*inv) << 16);
    pk.z = f2bf(acc[4]*inv) | (f2bf(acc[5]*inv) << 16);
    pk.w = f2bf(acc[6]*inv) | (f2bf(acc[7]*inv) << 16);
    out16[i*16 + m] = pk;
  }
}

// ---------------- BatchNorm stats from bf16 ----------------
__global__ __launch_bounds__(256) void k_bnstat(const unsigned int* __restrict__ x16,
                                                float* __restrict__ sums){
  int colu = threadIdx.x & 63;
  int ro   = threadIdx.x >> 6;
  float s0 = 0.f, s1 = 0.f, q0 = 0.f, q1 = 0.f;
  for (int r = blockIdx.x*4 + ro; r < N_NODES; r += gridDim.x*4){
    float2 v = bf2f2(x16[(size_t)r*64 + colu]);
    s0 += v.x; s1 += v.y; q0 += v.x*v.x; q1 += v.y*v.y;
  }
  __shared__ float rs0[256], rs1[256], rq0[256], rq1[256];
  int t = threadIdx.x;
  rs0[t] = s0; rs1[t] = s1; rq0[t] = q0; rq1[t] = q1;
  __syncthreads();
  if (t < 64){
    float S0 = rs0[t] + rs0[t+64] + rs0[t+128] + rs0[t+192];
    float S1 = rs1[t] + rs1[t+64] + rs1[t+128] + rs1[t+192];
    float Q0 = rq0[t] + rq0[t+64] + rq0[t+128] + rq0[t+192];
    float Q1 = rq1[t] + rq1[t+64] + rq1[t+128] + rq1[t+192];
    atomicAdd(&sums[2*t],       S0);
    atomicAdd(&sums[2*t + 1],   S1);
    atomicAdd(&sums[128 + 2*t],     Q0);
    atomicAdd(&sums[128 + 2*t + 1], Q1);
  }
}

// --------- BN apply (+opt bf16 residual) + lrelu; bf16 in/out ---------
__global__ void k_bnapply(const unsigned int* __restrict__ x16,
    const float* __restrict__ sums, const float* __restrict__ g,
    const float* __restrict__ b, const unsigned int* __restrict__ res16,
    unsigned int* __restrict__ y16){
  int f = blockIdx.x*256 + threadIdx.x;
  if (f >= N_NODES*32) return;
  int c = (f & 31) * 4;
  uint2 u = *(const uint2*)(x16 + (size_t)f*2);
  float2 vA = bf2f2(u.x), vB = bf2f2(u.y);
  float vv[4] = {vA.x, vA.y, vB.x, vB.y};
  float rr[4] = {0.f, 0.f, 0.f, 0.f};
  if (res16){
    uint2 ur = *(const uint2*)(res16 + (size_t)f*2);
    float2 rA = bf2f2(ur.x), rB = bf2f2(ur.y);
    rr[0]=rA.x; rr[1]=rA.y; rr[2]=rB.x; rr[3]=rB.y;
  }
  float o[4];
  const float invn = 1.f / (float)N_NODES;
  #pragma unroll
  for (int j = 0; j < 4; ++j){
    int cc = c + j;
    float mu  = sums[cc] * invn;
    float var = sums[128 + cc] * invn - mu*mu;
    float rs  = rsqrtf(var + EPSV);
    o[j] = lrelu((vv[j] - mu)*rs*g[cc] + b[cc] + rr[j]);
  }
  uint2 pk;
  pk.x = f2bf(o[0]) | (f2bf(o[1]) << 16);
  pk.y = f2bf(o[2]) | (f2bf(o[3]) << 16);
  *(uint2*)(y16 + (size_t)f*2) = pk;
}

// ---------------- global mean pool (bf16 input) ----------------
__global__ __launch_bounds__(256) void k_pool(const unsigned int* __restrict__ h16,
    const int* __restrict__ batch, float* __restrict__ pooled,
    float* __restrict__ cnt){
  int colu = threadIdx.x & 63;
  int ro   = threadIdx.x >> 6;
  int base = blockIdx.x * 128;
  int g_cur = -1; float a0 = 0.f, a1 = 0.f, cacc = 0.f;
  for (int ii = 0; ii < 32; ++ii){
    int r = base + ro + ii*4;
    if (r >= N_NODES) break;
    int g = batch[r];
    if (g != g_cur){
      if (g_cur >= 0){
        atomicAdd(&pooled[g_cur*D + 2*colu],     a0);
        atomicAdd(&pooled[g_cur*D + 2*colu + 1], a1);
        if (colu == 0) atomicAdd(&cnt[g_cur], cacc);
      }
      a0 = 0.f; a1 = 0.f; cacc = 0.f; g_cur = g;
    }
    float2 v = bf2f2(h16[(size_t)r*64 + colu]);
    a0 += v.x; a1 += v.y; cacc += 1.f;
  }
  if (g_cur >= 0){
    atomicAdd(&pooled[g_cur*D + 2*colu],     a0);
    atomicAdd(&pooled[g_cur*D + 2*colu + 1], a1);
    if (colu == 0) atomicAdd(&cnt[g_cur], cacc);
  }
}

// ---------------- final FC ----------------
__global__ void k_fc(const float* __restrict__ pooled, const float* __restrict__ cnt,
    const float* __restrict__ W, const float* __restrict__ b, float* __restrict__ out){
  int idx = blockIdx.x*256 + threadIdx.x;
  if (idx >= GR*64) return;
  int g = idx >> 6, o = idx & 63;
  const float* p = pooled + g*D;
  float s = 0.f;
  for (int c2 = 0; c2 < D; ++c2) s += p[c2] * W[c2*64 + o];
  float inv = 1.f / fmaxf(cnt[g], 1.f);
  out[idx] = s*inv + b[o];
}

extern "C" void kernel_launch(void* const* d_in, const int* in_sizes, int n_in,
                              void* d_out, int out_size, void* d_ws, size_t ws_size,
                              hipStream_t stream){
  (void)in_sizes; (void)n_in; (void)out_size; (void)ws_size;
  const float* x       = (const float*)d_in[0];
  const int*   ei      = (const int*)  d_in[1];
  const int*   batch   = (const int*)  d_in[2];
  const float* gat1_W  = (const float*)d_in[3];
  const float* gat1_as = (const float*)d_in[4];
  const float* gat1_ad = (const float*)d_in[5];
  const float* gat1_b  = (const float*)d_in[6];
  const float* gat2_W  = (const float*)d_in[7];
  const float* gat2_as = (const float*)d_in[8];
  const float* gat2_ad = (const float*)d_in[9];
  const float* gat2_b  = (const float*)d_in[10];
  const float* s3_Wl   = (const float*)d_in[11];
  const float* s3_bl   = (const float*)d_in[12];
  const float* s3_Wr   = (const float*)d_in[13];
  const float* s4_Wl   = (const float*)d_in[14];
  const float* s4_bl   = (const float*)d_in[15];
  const float* s4_Wr   = (const float*)d_in[16];
  const float* s5_Wl   = (const float*)d_in[17];
  const float* s5_bl   = (const float*)d_in[18];
  const float* s5_Wr   = (const float*)d_in[19];
  const float* bn1_g = (const float*)d_in[20]; const float* bn1_b = (const float*)d_in[21];
  const float* bn2_g = (const float*)d_in[22]; const float* bn2_b = (const float*)d_in[23];
  const float* bn3_g = (const float*)d_in[24]; const float* bn3_b = (const float*)d_in[25];
  const float* bn4_g = (const float*)d_in[26]; const float* bn4_b = (const float*)d_in[27];
  const float* bn5_g = (const float*)d_in[28]; const float* bn5_b = (const float*)d_in[29];
  const float* res1_W = (const float*)d_in[30]; const float* res1_b = (const float*)d_in[31];
  const float* res2_W = (const float*)d_in[32]; const float* res2_b = (const float*)d_in[33];
  const float* fc_W   = (const float*)d_in[34]; const float* fc_b   = (const float*)d_in[35];
  float* out = (float*)d_out;

  char* ws = (char*)d_ws;
  size_t off = 0;
  auto alloc = [&](size_t bytes) -> void* {
    void* p = ws + off; off += (bytes + 255) & ~(size_t)255; return p;
  };
  const int mgrid = (N_NODES + 63) / 64;
  int*   rowStart = (int*)  alloc((N_NODES + 1) * 4);
  int*   rank     = (int*)  alloc((size_t)N_EDGES * 4);
  int*   srcList  = (int*)  alloc((size_t)N_EDGES * 4);
  int*   bsum     = (int*)  alloc(256 * 4);
  // ---- contiguous zero region: deg | bnsums | pooled | cnt ----
  size_t zoff0 = off;
  int*   deg      = (int*)  alloc((size_t)N_NODES * 4);
  float* bnsums   = (float*)alloc(5 * 256 * 4);
  float* pooled   = (float*)alloc(GR * D * 4);
  float* cnt      = (float*)alloc(64 * 4);
  size_t zbytes = off - zoff0;
  float* es       = (float*)alloc((size_t)N_NODES * 4 * 4);
  float* edv      = (float*)alloc((size_t)N_NODES * 4 * 4);
  float* bnpart   = (float*)alloc((size_t)mgrid * 256 * 4);
  unsigned short* Wt16 = (unsigned short*)alloc(10 * 16384 * 2);
  unsigned short* HX   = (unsigned short*)alloc((size_t)N_NODES * D * 2);
  unsigned short* H16a = (unsigned short*)alloc((size_t)N_NODES * D * 2);
  unsigned short* HO   = (unsigned short*)alloc((size_t)N_NODES * D * 2);
  unsigned short* HR   = (unsigned short*)alloc((size_t)N_NODES * D * 2);

  const int* srcE = ei;
  const int* dstE = ei + N_EDGES;
  const int nb = (N_NODES + 255) / 256;
  const int egrid = (N_EDGES + 255) / 256;
  const int agrid = (N_NODES + 3) / 4;
  const int bgrid = (N_NODES*32 + 255) / 256;
  const int pgrid = (N_NODES + 127) / 128;

  // single zeroing memset + CSR build
  hipMemsetAsync(ws + zoff0, 0, zbytes, stream);
  k_countrank<<<egrid, 256, 0, stream>>>(dstE, deg, rank);
  k_scan1<<<nb, 256, 0, stream>>>(deg, bsum);
  k_scan2b<<<1, 256, 0, stream>>>(bsum, nb, rowStart);
  k_scan3<<<nb, 256, 0, stream>>>(deg, bsum, rowStart);
  k_scatter<<<egrid, 256, 0, stream>>>(srcE, dstE, rank, rowStart, srcList);

  // fused casts (weights + x)
  WPack wp;
  wp.w[0]=res1_W; wp.w[1]=gat1_W; wp.w[2]=res2_W; wp.w[3]=gat2_W;
  wp.w[4]=s3_Wl;  wp.w[5]=s3_Wr;  wp.w[6]=s4_Wl;  wp.w[7]=s4_Wr;
  wp.w[8]=s5_Wl;  wp.w[9]=s5_Wr;
  k_casts<<<640 + bgrid, 256, 0, stream>>>(wp, Wt16, x, HX);

  // ---- layer 1 (GAT) ----
  k_mgemm_dual<<<mgrid, 256, 0, stream>>>(HX, Wt16 + 0*16384, Wt16 + 1*16384,
                                          res1_b, gat1_as, gat1_ad,
                                          HR, H16a, es, edv, N_NODES);
  k_gat<<<agrid, 256, 0, stream>>>((const uint4*)H16a, es, edv, rowStart,
                                   srcList, gat1_b, (uint4*)HO);
  k_bnstat<<<256, 256, 0, stream>>>((const unsigned int*)HO, bnsums);
  k_bnapply<<<bgrid, 256, 0, stream>>>((const unsigned int*)HO, bnsums, bn1_g, bn1_b,
                                       (const unsigned int*)HR, (unsigned int*)H16a);

  // ---- layer 2 (GAT) ----
  k_mgemm_dual<<<mgrid, 256, 0, stream>>>(H16a, Wt16 + 2*16384, Wt16 + 3*16384,
                                          res2_b, gat2_as, gat2_ad,
                                          HR, HX, es, edv, N_NODES);
  k_gat<<<agrid, 256, 0, stream>>>((const uint4*)HX, es, edv, rowStart,
                                   srcList, gat2_b, (uint4*)HO);
  k_bnstat<<<256, 256, 0, stream>>>((const unsigned int*)HO, bnsums + 256);
  k_bnapply<<<bgrid, 256, 0, stream>>>((const unsigned int*)HO, bnsums + 256, bn2_g, bn2_b,
                                       (const unsigned int*)HR, (unsigned int*)H16a);

  // ---- layer 3 (SAGE) ----
  k_sage_mean<<<agrid, 256, 0, stream>>>((const uint4*)H16a, rowStart, srcList,
                                         (uint4*)HX);
  k_mgemm2<<<mgrid, 256, 0, stream>>>(HX, Wt16 + 4*16384, H16a, Wt16 + 5*16384,
                                      s3_bl, HO, N_NODES, bnpart);
  k_bnred<<<64, 256, 0, stream>>>(bnpart, mgrid, bnsums + 512);
  k_bnapply<<<bgrid, 256, 0, stream>>>((const unsigned int*)HO, bnsums + 512, bn3_g, bn3_b,
                                       nullptr, (unsigned int*)H16a);

  // ---- layer 4 (SAGE) ----
  k_sage_mean<<<agrid, 256, 0, stream>>>((const uint4*)H16a, rowStart, srcList,
                                         (uint4*)HX);
  k_mgemm2<<<mgrid, 256, 0, stream>>>(HX, Wt16 + 6*16384, H16a, Wt16 + 7*16384,
                                      s4_bl, HO, N_NODES, bnpart);
  k_bnred<<<64, 256, 0, stream>>>(bnpart, mgrid, bnsums + 768);
  k_bnapply<<<bgrid, 256, 0, stream>>>((const unsigned int*)HO, bnsums + 768, bn4_g, bn4_b,
                                       nullptr, (unsigned int*)H16a);

  // ---- layer 5 (SAGE) ----
  k_sage_mean<<<agrid, 256, 0, stream>>>((const uint4*)H16a, rowStart, srcList,
                                         (uint4*)HX);
  k_mgemm2<<<mgrid, 256, 0, stream>>>(HX, Wt16 + 8*16384, H16a, Wt16 + 9*16384,
                                      s5_bl, HO, N_NODES, bnpart);
  k_bnred<<<64, 256, 0, stream>>>(bnpart, mgrid, bnsums + 1024);
  k_bnapply<<<bgrid, 256, 0, stream>>>((const unsigned int*)HO, bnsums + 1024, bn5_g, bn5_b,
                                       nullptr, (unsigned int*)H16a);

  // ---- pool + fc ----
  k_pool<<<pgrid, 256, 0, stream>>>((const unsigned int*)H16a, batch, pooled, cnt);
  k_fc<<<(GR*64 + 255)/256, 256, 0, stream>>>(pooled, cnt, fc_W, fc_b, out);
}